// Round 6
// baseline (1209.949 us; speedup 1.0000x reference)
//
#include <hip/hip_runtime.h>
#include <cstddef>

// Problem constants
constexpr int Bn  = 512;
constexpr int Dd  = 960;
constexpr int RL  = 16;
constexpr int RD  = 32;
constexpr int LPp = 16;
constexpr int LHh = 384;
constexpr int DP  = 358;
constexpr int DH  = 154;
constexpr int SEGH  = 192;  // H l-segment rows
constexpr int DHALF = 480;  // d-half width

typedef float  f32x4 __attribute__((ext_vector_type(4)));
typedef float  f32x2 __attribute__((ext_vector_type(2)));

// =====================================================================
// K0: zero the per-batch arrival counters (ws is poisoned 0xAA).
// =====================================================================
__global__ void zero_kernel(int* __restrict__ cnt, int n)
{
    int i = blockIdx.x * 256 + threadIdx.x;
    if (i < n) cnt[i] = 0;
}

// =====================================================================
// K1: fused stream + partial-U + (last block per batch) z.
// Work unit = (batch, l-segment, d-half):
//   H: 512 b x 2 seg x 2 half = 2048 blocks, granule <= 192x480 floats
//   P: 512 b x 1 seg x 2 half = 1024 blocks
// Per block: len = popcount(mask row); stream X rows [l0,l1) cols
// [d0,d0+480) via nontemporal float2 (240 lanes x 8B, coalesced);
// V-quadrant accumulated in 32 VGPRs -> LDS (16x480, 30KB -> 4 blk/CU);
// partial U[p][r] over this quadrant -> slot; threadfence + counter.
// Last-arriving block of the batch sums slots (fixed order) and
// computes z[b][:] = vec(U) @ Hc  (overlapped with other blocks' streams).
// =====================================================================
__global__ __launch_bounds__(256)
void fused_kernel(const float* __restrict__ XH, const int* __restrict__ mH,
                  const float* __restrict__ AH, const float* __restrict__ BcH,
                  const float* __restrict__ HcH,
                  const float* __restrict__ XP, const int* __restrict__ mP,
                  const float* __restrict__ AP, const float* __restrict__ BcP,
                  const float* __restrict__ HcP,
                  float* __restrict__ UH, float* __restrict__ UP,
                  int* __restrict__ cntH, int* __restrict__ cntP,
                  float* __restrict__ zH, float* __restrict__ zP)
{
    const int id = blockIdx.x;
    const bool isH = (id < 2048);
    int b, seg, half;
    const float *X, *A, *Bc, *Hc; const int* mask;
    float *slots, *z; int* cnt;
    int L, seglen, dmod, nslot;
    if (isH) {
        b = id >> 2; seg = (id >> 1) & 1; half = id & 1;
        X = XH; mask = mH; A = AH; Bc = BcH; Hc = HcH;
        L = LHh; seglen = SEGH; dmod = DH; nslot = 4;
        slots = UH + (size_t)b * 4 * 512;
        cnt = cntH + b; z = zH;
    } else {
        const int r = id - 2048;
        b = r >> 1; seg = 0; half = r & 1;
        X = XP; mask = mP; A = AP; Bc = BcP; Hc = HcP;
        L = LPp; seglen = LPp; dmod = DP; nslot = 2;
        slots = UP + (size_t)b * 2 * 512;
        cnt = cntP + b; z = zP;
    }
    const int t = threadIdx.x;

    __shared__ float Vs[RL][DHALF + 4];   // pitch 484 (16B-aligned rows)
    __shared__ float Ush[RL * RD];
    __shared__ int   s_len, s_last;

    // ---- len = popcount of contiguous-prefix mask row ----
    if (t == 0) s_len = 0;
    __syncthreads();
    int loc = 0;
    for (int i = t; i < L; i += 256) loc += mask[(size_t)b * L + i];
    if (loc) atomicAdd(&s_len, loc);
    __syncthreads();
    const int len = __builtin_amdgcn_readfirstlane(s_len);

    const int l0 = seg * seglen;
    const int l1 = min(len, l0 + seglen);
    const int d0 = half * DHALF;

    float u0 = 0.f, u1 = 0.f;
    if (l1 > l0) {                       // block-uniform branch
        // ---- stream phase: V-quadrant in registers ----
        if (t < 240) {
            float v[RL][2];
            #pragma unroll
            for (int p = 0; p < RL; ++p) { v[p][0] = 0.f; v[p][1] = 0.f; }
            const float* xrow = X + ((size_t)b * L + l0) * Dd + d0 + 2 * t;
            for (int l = l0; l < l1; ++l) {
                f32x2 xv = __builtin_nontemporal_load((const f32x2*)xrow);
                xrow += Dd;
                float a[RL];
                *(f32x4*)&a[0]  = *(const f32x4*)(A + (size_t)l * RL + 0);
                *(f32x4*)&a[4]  = *(const f32x4*)(A + (size_t)l * RL + 4);
                *(f32x4*)&a[8]  = *(const f32x4*)(A + (size_t)l * RL + 8);
                *(f32x4*)&a[12] = *(const f32x4*)(A + (size_t)l * RL + 12);
                #pragma unroll
                for (int p = 0; p < RL; ++p) {
                    v[p][0] = fmaf(a[p], xv[0], v[p][0]);
                    v[p][1] = fmaf(a[p], xv[1], v[p][1]);
                }
            }
            #pragma unroll
            for (int p = 0; p < RL; ++p)
                *(f32x2*)&Vs[p][2 * t] = *(f32x2*)&v[p][0];
        }
        __syncthreads();

        // ---- partial U over this quadrant ----
        const int p = t >> 5, r = t & 31;
        for (int dd = 0; dd < DHALF; dd += 4) {
            f32x4 a0 = *(const f32x4*)&Vs[p][dd];
            f32x4 a1 = *(const f32x4*)&Vs[p + 8][dd];
            #pragma unroll
            for (int q = 0; q < 4; ++q) {
                float bc = Bc[(size_t)(d0 + dd + q) * RD + r];
                u0 = fmaf(a0[q], bc, u0);
                u1 = fmaf(a1[q], bc, u1);
            }
        }
    }

    // ---- publish slot (dead quadrants publish zeros) ----
    float* slot = slots + (size_t)(seg * 2 + half) * 512;
    slot[t]       = u0;    // flat p*32+r == t
    slot[t + 256] = u1;    // flat (p+8)*32+r == t+256
    __threadfence();       // release own writes to device scope
    __syncthreads();
    if (t == 0) {
        int old = atomicAdd(cnt, 1);
        s_last = (old == nslot - 1);
    }
    __syncthreads();
    if (!s_last) return;

    // ---- last block of this batch: sum slots, compute z ----
    __threadfence();       // acquire other blocks' slot writes
    {
        float a0 = 0.f, a1 = 0.f;
        for (int s = 0; s < nslot; ++s) {
            a0 += slots[(size_t)s * 512 + t];
            a1 += slots[(size_t)s * 512 + t + 256];
        }
        Ush[t]       = a0;
        Ush[t + 256] = a1;
    }
    __syncthreads();
    for (int j = t; j < dmod; j += 256) {
        float acc0 = 0.f, acc1 = 0.f;
        #pragma unroll 8
        for (int i = 0; i < RL * RD; i += 2) {
            acc0 = fmaf(Ush[i],     Hc[(size_t)i * dmod + j],       acc0);
            acc1 = fmaf(Ush[i + 1], Hc[(size_t)(i + 1) * dmod + j], acc1);
        }
        z[(size_t)b * dmod + j] = acc0 + acc1;
    }
}

// =====================================================================
// K2/K3 mlp2: C = A(512,K) @ W(K,N) + bias, P and H fused in one grid.
//   MODE 0: h = relu(C * g/sqrt(1+eps) + beta) -> out (512,N) pitch N
//   MODE 1: C -> d_out[m*(DP+DH) + ooff + c]   (concat store)
// =====================================================================
template <int MODE>
__global__ __launch_bounds__(256)
void mlp2_kernel(const float* __restrict__ AaP, const float* __restrict__ WP,
                 const float* __restrict__ biasP, const float* __restrict__ gPv,
                 const float* __restrict__ betaPv, float* __restrict__ outP,
                 const float* __restrict__ AaH, const float* __restrict__ WH,
                 const float* __restrict__ biasH, const float* __restrict__ gHv,
                 const float* __restrict__ betaHv, float* __restrict__ outH,
                 int nbP)
{
    const float *Aa, *W, *bias, *g, *beta; float* out;
    int K, N, n0, ooff;
    if ((int)blockIdx.y < nbP) {
        Aa = AaP; W = WP; bias = biasP; g = gPv; beta = betaPv; out = outP;
        K = DP; N = DP; n0 = blockIdx.y * 64; ooff = 0;
    } else {
        Aa = AaH; W = WH; bias = biasH; g = gHv; beta = betaHv; out = outH;
        K = DH; N = DH; n0 = (blockIdx.y - nbP) * 64; ooff = DP;
    }
    const int ostride = (MODE == 0) ? N : (DP + DH);
    if (MODE == 0) ooff = 0;

    constexpr int TM = 64, TN = 64, KC = 32;
    __shared__ float AsT[KC][TM + 4];
    __shared__ float Ws[KC][TN];
    const int t  = threadIdx.x;
    const int m0 = blockIdx.x * TM;
    const int r0 = (t >> 4) << 2;
    const int c0 = (t & 15) << 2;
    float acc[4][4] = {};

    for (int k0 = 0; k0 < K; k0 += KC) {
        for (int i = t; i < TM * KC; i += 256) {
            int row = i >> 5, kk = i & 31;
            int kg = k0 + kk;
            AsT[kk][row] = (kg < K) ? Aa[(size_t)(m0 + row) * K + kg] : 0.f;
        }
        for (int i = t; i < KC * TN; i += 256) {
            int kk = i >> 6, c = i & 63;
            int kg = k0 + kk, cg = n0 + c;
            Ws[kk][c] = (kg < K && cg < N) ? W[(size_t)kg * N + cg] : 0.f;
        }
        __syncthreads();
        #pragma unroll
        for (int kk = 0; kk < KC; ++kk) {
            float4 av = *(const float4*)&AsT[kk][r0];
            float4 wv = *(const float4*)&Ws[kk][c0];
            const float a[4] = {av.x, av.y, av.z, av.w};
            const float w[4] = {wv.x, wv.y, wv.z, wv.w};
            #pragma unroll
            for (int i = 0; i < 4; ++i)
                #pragma unroll
                for (int j = 0; j < 4; ++j)
                    acc[i][j] = fmaf(a[i], w[j], acc[i][j]);
        }
        __syncthreads();
    }

    const float bscale = rsqrtf(1.f + 1e-5f);
    #pragma unroll
    for (int j = 0; j < 4; ++j) {
        int c = n0 + c0 + j;
        if (c < N) {
            float bb = bias[c];
            float gg = 0.f, be = 0.f;
            if constexpr (MODE == 0) { gg = g[c] * bscale; be = beta[c]; }
            #pragma unroll
            for (int i = 0; i < 4; ++i) {
                int m = m0 + r0 + i;
                float v = acc[i][j] + bb;
                if constexpr (MODE == 0) {
                    v = fmaf(v, gg, be);
                    v = fmaxf(v, 0.f);
                    out[(size_t)m * N + c] = v;
                } else {
                    out[(size_t)m * ostride + ooff + c] = v;
                }
            }
        }
    }
}

// =====================================================================
extern "C" void kernel_launch(void* const* d_in, const int* in_sizes, int n_in,
                              void* d_out, int out_size, void* d_ws, size_t ws_size,
                              hipStream_t stream)
{
    const float* emb_P  = (const float*)d_in[0];
    const float* emb_H  = (const float*)d_in[1];
    const int*   mask_P = (const int*)  d_in[2];
    const int*   mask_H = (const int*)  d_in[3];
    const float* B_cP   = (const float*)d_in[4];
    const float* A_cP   = (const float*)d_in[5];
    const float* H_cP   = (const float*)d_in[6];
    const float* W1P    = (const float*)d_in[7];
    const float* b1P    = (const float*)d_in[8];
    const float* gP     = (const float*)d_in[9];
    const float* betaP  = (const float*)d_in[10];
    const float* W2P    = (const float*)d_in[11];
    const float* b2P    = (const float*)d_in[12];
    const float* B_cH   = (const float*)d_in[13];
    const float* A_cH   = (const float*)d_in[14];
    const float* H_cH   = (const float*)d_in[15];
    const float* W1H    = (const float*)d_in[16];
    const float* b1H    = (const float*)d_in[17];
    const float* gH     = (const float*)d_in[18];
    const float* betaH  = (const float*)d_in[19];
    const float* W2H    = (const float*)d_in[20];
    const float* b2H    = (const float*)d_in[21];
    float* outp = (float*)d_out;

    // workspace layout (floats)
    float* ws  = (float*)d_ws;
    float* U_H = ws;                            // 512*4*512 = 1,048,576
    float* U_P = U_H + (size_t)Bn * 4 * 512;    // 512*2*512 =   524,288
    float* z_P = U_P + (size_t)Bn * 2 * 512;    // 512*358
    float* z_H = z_P + (size_t)Bn * DP;         // 512*154
    float* h_P = z_H + (size_t)Bn * DH;         // 512*358
    float* h_H = h_P + (size_t)Bn * DP;         // 512*154
    int*   cnt = (int*)(h_H + (size_t)Bn * DH); // 1024 ints
    int*   cntH = cnt;
    int*   cntP = cnt + Bn;

    dim3 blk(256);

    // K0: zero arrival counters (ws is poisoned)
    zero_kernel<<<dim3(4), blk, 0, stream>>>(cnt, 2 * Bn);

    // K1: fused stream + partial U + last-block z
    fused_kernel<<<dim3(3 * Bn * 2), blk, 0, stream>>>(
        emb_H, mask_H, A_cH, B_cH, H_cH,
        emb_P, mask_P, A_cP, B_cP, H_cP,
        U_H, U_P, cntH, cntP, z_H, z_P);

    // K2: layer 1 (BN-scale + ReLU): P tiles y=0..5, H tiles y=6..8
    mlp2_kernel<0><<<dim3(8, 9), blk, 0, stream>>>(
        z_P, W1P, b1P, gP, betaP, h_P,
        z_H, W1H, b1H, gH, betaH, h_H, 6);

    // K3: layer 2 + concat store into d_out
    mlp2_kernel<1><<<dim3(8, 9), blk, 0, stream>>>(
        h_P, W2P, b2P, nullptr, nullptr, outp,
        h_H, W2H, b2H, nullptr, nullptr, outp, 6);
}

// Round 7
// 256.176 us; speedup vs baseline: 4.7231x; 4.7231x over previous
//
#include <hip/hip_runtime.h>
#include <cstddef>

// Problem constants
constexpr int Bn  = 512;
constexpr int Dd  = 960;
constexpr int RL  = 16;
constexpr int RD  = 32;
constexpr int LPp = 16;
constexpr int LHh = 384;
constexpr int DP  = 358;
constexpr int DH  = 154;

typedef float f32x4 __attribute__((ext_vector_type(4)));

struct EncParams {
    const float* X;     // (B, L, 960)
    const int*   mask;  // (B, L) contiguous prefix
    const float* A;     // (L, 16)
    const float* Bc;    // (960, 32)
    const float* Hc;    // (512, dmod)
    const float* W1; const float* b1; const float* g; const float* beta;
    const float* W2; const float* b2;
    int L, dmod, ooff;
};

// =====================================================================
// K0: zero the work-queue counter (ws is poisoned 0xAA by harness).
// =====================================================================
__global__ void zero_kernel(int* __restrict__ q)
{
    if (threadIdx.x == 0) *q = 0;
}

// =====================================================================
// K1: persistent fused per-batch encoder.
// Grid = 512 blocks = exact residency (61.5 KB LDS -> 2 blocks/CU).
// Items 0..511 = H batches (heavy first -> LPT), 512..1023 = P batches.
// Per item (round-3 proven body):
//   stream: V[p][d] = sum_{l<len} A[l][p] * X[l][d]  (regs -> Vs LDS)
//           manual 2-row unroll, f32x4 NT loads, 2 rows in flight/wave
//   U:      U[p][r] = sum_d Vs[p][d] * Bc[d][r]      (-> Ush)
//   z:      z[j] = sum_i Ush[i] * Hc[i][j]           (-> zs, reuses Vs)
//   MLP1:   h = relu(bn(z @ W1 + b1))                (-> hs)
//   MLP2:   out[b, ooff+c] = h @ W2 + b2             (concat store)
// Dynamic stealing smooths the len~U[1,384] skew that made round 3's
// static 1024-block grid finish on the slowest CU (249us tail).
// =====================================================================
__global__ __launch_bounds__(256)
void persist_kernel(EncParams H, EncParams P, int* __restrict__ qcnt,
                    float* __restrict__ out)
{
    const int t = threadIdx.x;
    __shared__ float Vs[RL][Dd];    // 61440 B (zs/hs reuse after U phase)
    __shared__ float Ush[RL * RD];  // 2048 B
    __shared__ int   s_item, s_len;

    for (;;) {
        __syncthreads();                 // protect LDS reuse across items
        if (t == 0) { s_item = atomicAdd(qcnt, 1); s_len = 0; }
        __syncthreads();
        const int item = s_item;
        if (item >= 2 * Bn) return;
        const bool isH = (item < Bn);
        const EncParams E = isH ? H : P;
        const int b = isH ? item : item - Bn;

        // ---- len = popcount of contiguous-prefix mask row ----
        int loc = 0;
        for (int i = t; i < E.L; i += 256) loc += E.mask[(size_t)b * E.L + i];
        if (loc) atomicAdd(&s_len, loc);
        __syncthreads();
        const int len = s_len;

        // ---- stream phase: V = A^T Xm, 2-row software pipeline ----
        if (t < 240) {                   // 240 lanes x 4 d-cols = 960
            float v[RL][4];
            #pragma unroll
            for (int p = 0; p < RL; ++p)
                #pragma unroll
                for (int q = 0; q < 4; ++q) v[p][q] = 0.f;

            const float* xrow = E.X + (size_t)b * E.L * Dd + 4 * t;
            int l = 0;
            for (; l + 1 < len; l += 2) {
                // issue both rows' loads before any use
                f32x4 xv0 = __builtin_nontemporal_load((const f32x4*)xrow);
                f32x4 xv1 = __builtin_nontemporal_load((const f32x4*)(xrow + Dd));
                xrow += 2 * Dd;
                float a0[RL], a1[RL];
                *(f32x4*)&a0[0]  = *(const f32x4*)(E.A + (size_t)l * RL + 0);
                *(f32x4*)&a0[4]  = *(const f32x4*)(E.A + (size_t)l * RL + 4);
                *(f32x4*)&a0[8]  = *(const f32x4*)(E.A + (size_t)l * RL + 8);
                *(f32x4*)&a0[12] = *(const f32x4*)(E.A + (size_t)l * RL + 12);
                *(f32x4*)&a1[0]  = *(const f32x4*)(E.A + (size_t)(l + 1) * RL + 0);
                *(f32x4*)&a1[4]  = *(const f32x4*)(E.A + (size_t)(l + 1) * RL + 4);
                *(f32x4*)&a1[8]  = *(const f32x4*)(E.A + (size_t)(l + 1) * RL + 8);
                *(f32x4*)&a1[12] = *(const f32x4*)(E.A + (size_t)(l + 1) * RL + 12);
                #pragma unroll
                for (int p = 0; p < RL; ++p) {
                    #pragma unroll
                    for (int q = 0; q < 4; ++q)
                        v[p][q] = fmaf(a0[p], xv0[q], v[p][q]);
                }
                #pragma unroll
                for (int p = 0; p < RL; ++p) {
                    #pragma unroll
                    for (int q = 0; q < 4; ++q)
                        v[p][q] = fmaf(a1[p], xv1[q], v[p][q]);
                }
            }
            if (l < len) {
                f32x4 xv = __builtin_nontemporal_load((const f32x4*)xrow);
                float a[RL];
                *(f32x4*)&a[0]  = *(const f32x4*)(E.A + (size_t)l * RL + 0);
                *(f32x4*)&a[4]  = *(const f32x4*)(E.A + (size_t)l * RL + 4);
                *(f32x4*)&a[8]  = *(const f32x4*)(E.A + (size_t)l * RL + 8);
                *(f32x4*)&a[12] = *(const f32x4*)(E.A + (size_t)l * RL + 12);
                #pragma unroll
                for (int p = 0; p < RL; ++p)
                    #pragma unroll
                    for (int q = 0; q < 4; ++q)
                        v[p][q] = fmaf(a[p], xv[q], v[p][q]);
            }
            #pragma unroll
            for (int p = 0; p < RL; ++p)
                *(f32x4*)&Vs[p][4 * t] = *(f32x4*)&v[p][0];
        }
        __syncthreads();

        // ---- U phase: U = V * Bc ----
        {
            const int p = t >> 5, r = t & 31;
            float u0 = 0.f, u1 = 0.f;
            for (int dd = 0; dd < Dd; dd += 4) {
                f32x4 v0 = *(const f32x4*)&Vs[p][dd];
                f32x4 v1 = *(const f32x4*)&Vs[p + 8][dd];
                #pragma unroll
                for (int q = 0; q < 4; ++q) {
                    float bc = E.Bc[(size_t)(dd + q) * RD + r];
                    u0 = fmaf(v0[q], bc, u0);
                    u1 = fmaf(v1[q], bc, u1);
                }
            }
            Ush[p * RD + r]       = u0;
            Ush[(p + 8) * RD + r] = u1;
        }
        __syncthreads();

        // ---- z phase: z = vec(U) @ Hc  (zs/hs reuse dead Vs space) ----
        float* zs = &Vs[0][0];
        float* hs = &Vs[0][0] + 512;
        for (int j = t; j < E.dmod; j += 256) {
            float acc0 = 0.f, acc1 = 0.f;
            #pragma unroll 8
            for (int i = 0; i < RL * RD; i += 2) {
                acc0 = fmaf(Ush[i],     E.Hc[(size_t)i * E.dmod + j],       acc0);
                acc1 = fmaf(Ush[i + 1], E.Hc[(size_t)(i + 1) * E.dmod + j], acc1);
            }
            zs[j] = acc0 + acc1;
        }
        __syncthreads();

        // ---- MLP layer 1 + BN + ReLU ----
        const float bscale = rsqrtf(1.f + 1e-5f);
        for (int c = t; c < E.dmod; c += 256) {
            float acc = E.b1[c];
            #pragma unroll 4
            for (int k = 0; k < E.dmod; ++k)
                acc = fmaf(zs[k], E.W1[(size_t)k * E.dmod + c], acc);
            acc = fmaf(acc, E.g[c] * bscale, E.beta[c]);
            hs[c] = fmaxf(acc, 0.f);
        }
        __syncthreads();

        // ---- MLP layer 2 + concat store ----
        for (int c = t; c < E.dmod; c += 256) {
            float acc = E.b2[c];
            #pragma unroll 4
            for (int k = 0; k < E.dmod; ++k)
                acc = fmaf(hs[k], E.W2[(size_t)k * E.dmod + c], acc);
            out[(size_t)b * (DP + DH) + E.ooff + c] = acc;
        }
        // loop: top-of-loop __syncthreads protects Vs/Ush reuse
    }
}

// =====================================================================
extern "C" void kernel_launch(void* const* d_in, const int* in_sizes, int n_in,
                              void* d_out, int out_size, void* d_ws, size_t ws_size,
                              hipStream_t stream)
{
    EncParams P, H;
    P.X    = (const float*)d_in[0];
    H.X    = (const float*)d_in[1];
    P.mask = (const int*)  d_in[2];
    H.mask = (const int*)  d_in[3];
    P.Bc   = (const float*)d_in[4];
    P.A    = (const float*)d_in[5];
    P.Hc   = (const float*)d_in[6];
    P.W1   = (const float*)d_in[7];
    P.b1   = (const float*)d_in[8];
    P.g    = (const float*)d_in[9];
    P.beta = (const float*)d_in[10];
    P.W2   = (const float*)d_in[11];
    P.b2   = (const float*)d_in[12];
    H.Bc   = (const float*)d_in[13];
    H.A    = (const float*)d_in[14];
    H.Hc   = (const float*)d_in[15];
    H.W1   = (const float*)d_in[16];
    H.b1   = (const float*)d_in[17];
    H.g    = (const float*)d_in[18];
    H.beta = (const float*)d_in[19];
    H.W2   = (const float*)d_in[20];
    H.b2   = (const float*)d_in[21];
    P.L = LPp;  P.dmod = DP;  P.ooff = 0;
    H.L = LHh;  H.dmod = DH;  H.ooff = DP;

    float* outp = (float*)d_out;
    int*   qcnt = (int*)d_ws;

    zero_kernel<<<dim3(1), dim3(64), 0, stream>>>(qcnt);
    persist_kernel<<<dim3(512), dim3(256), 0, stream>>>(H, P, qcnt, outp);
}